// Round 4
// baseline (354.174 us; speedup 1.0000x reference)
//
#include <hip/hip_runtime.h>
#include <math.h>

// Problem constants (setup_inputs: bs=16, nq=550, nc=91, nt=48, group_num=11)
#define BS 16
#define NQ 550
#define NC 91
#define NT 48
#define GN 11
#define GQ 50                 // queries per group
#define NTOT (BS * NT)        // 768
#define NROW 48               // LSA rows (targets) after reference transpose
#define MCOL 50               // LSA cols (queries)
#define NPAIR (GN * NT)       // 528
#define NLSA (BS * GN)        // 176 LSA blocks
#define LPAD 51               // LDS tile row stride (f32)

// ---------------- focal (class) cost: fast f32 ------------------------------
// Native v_exp/v_log (~1e-5 abs error). We already run 0.125 from the np-f64
// reference (threshold 10.96) with matching assignments -> margins >= ~0.25;
// 1e-5 perturbation is 4 orders below that. Same inline fn feeds both the C
// write and the LSA tile.
__device__ __forceinline__ float focal_cost_f32(float x) {
    float prob = 1.0f / (1.0f + __expf(-x));
    float q = 1.0f - prob;
    float lneg = __logf(q + 1e-8f);
    float lpos = __logf(prob + 1e-8f);
    float neg = 0.75f * (prob * prob) * (-lneg);
    float pos = 0.25f * (q * q) * (-lpos);
    return pos - neg;
}

// ---------------- one C element, f32 __f*_rn box math ------------------------
__device__ __forceinline__ float cost_element(
    const float* __restrict__ logits,
    const float* __restrict__ pboxes, const int* __restrict__ labels,
    const float* __restrict__ tboxes, int p, int t)
{
    const float* pb = pboxes + (long)p * 6;
    float pcx = pb[0], pcy = pb[1], pl = pb[2], pr = pb[3], ptt = pb[4], pbo = pb[5];
    const float* tb = tboxes + (long)t * 6;
    float tcx = tb[0], tcy = tb[1], tl = tb[2], tr = tb[3], ttt = tb[4], tbo = tb[5];

    float c3d = __fadd_rn(fabsf(__fsub_rn(pcx, tcx)), fabsf(__fsub_rn(pcy, tcy)));
    float cbb = __fadd_rn(
                  __fadd_rn(
                    __fadd_rn(fabsf(__fsub_rn(pl, tl)), fabsf(__fsub_rn(pr, tr))),
                    fabsf(__fsub_rn(ptt, ttt))),
                  fabsf(__fsub_rn(pbo, tbo)));

    float px1 = __fsub_rn(pcx, pl), py1 = __fsub_rn(pcy, ptt);
    float px2 = __fadd_rn(pcx, pr), py2 = __fadd_rn(pcy, pbo);
    float tx1 = __fsub_rn(tcx, tl), ty1 = __fsub_rn(tcy, ttt);
    float tx2 = __fadd_rn(tcx, tr), ty2 = __fadd_rn(tcy, tbo);

    float area1 = __fmul_rn(__fsub_rn(px2, px1), __fsub_rn(py2, py1));
    float area2 = __fmul_rn(__fsub_rn(tx2, tx1), __fsub_rn(ty2, ty1));
    float ltx = fmaxf(px1, tx1), lty = fmaxf(py1, ty1);
    float rbx = fminf(px2, tx2), rby = fminf(py2, ty2);
    float wx = fmaxf(__fsub_rn(rbx, ltx), 0.0f);
    float wy = fmaxf(__fsub_rn(rby, lty), 0.0f);
    float inter = __fmul_rn(wx, wy);
    float uni = __fsub_rn(__fadd_rn(area1, area2), inter);
    float iou = __fdiv_rn(inter, uni);
    float ex1 = fminf(px1, tx1), ey1 = fminf(py1, ty1);
    float ex2 = fmaxf(px2, tx2), ey2 = fmaxf(py2, ty2);
    float ew = fmaxf(__fsub_rn(ex2, ex1), 0.0f);
    float eh = fmaxf(__fsub_rn(ey2, ey1), 0.0f);
    float earea = __fmul_rn(ew, eh);
    float giou = __fsub_rn(iou, __fdiv_rn(__fsub_rn(earea, uni), earea));
    float cgiou = -giou;

    float cclass = focal_cost_f32(logits[(long)p * NC + labels[t]]);

    float out = __fmul_rn(5.0f, cbb);
    out = __fadd_rn(out, __fmul_rn(10.0f, c3d));
    out = __fadd_rn(out, __fmul_rn(2.0f, cclass));
    out = __fadd_rn(out, __fmul_rn(2.0f, cgiou));
    return out;
}

// ---------------- cross-lane f64 helpers ------------------------------------
__device__ __forceinline__ double readlane_f64(double x, int l) {
    long long b = __double_as_longlong(x);
    int lo = __builtin_amdgcn_readlane((int)(b & 0xffffffffLL), l);
    int hi = __builtin_amdgcn_readlane((int)(b >> 32), l);
    return __longlong_as_double(((long long)hi << 32) | (unsigned int)lo);
}

template <int CTRL, int RM>
__device__ __forceinline__ double dpp_min_f64(double x) {
    long long b = __double_as_longlong(x);
    int lo = (int)(b & 0xffffffffLL);
    int hi = (int)(b >> 32);
    int tlo = __builtin_amdgcn_update_dpp(lo, lo, CTRL, RM, 0xf, false);
    int thi = __builtin_amdgcn_update_dpp(hi, hi, CTRL, RM, 0xf, false);
    double t = __longlong_as_double(((long long)thi << 32) | (unsigned int)tlo);
    return fmin(x, t);   // v_min_f64; NaNs impossible here
}

__device__ __forceinline__ double wave_min_f64(double val) {
    double r = val;
    r = dpp_min_f64<0x111, 0xf>(r);  // row_shr:1
    r = dpp_min_f64<0x112, 0xf>(r);  // row_shr:2
    r = dpp_min_f64<0x114, 0xf>(r);  // row_shr:4
    r = dpp_min_f64<0x118, 0xf>(r);  // row_shr:8
    r = dpp_min_f64<0x142, 0xa>(r);  // row_bcast:15
    r = dpp_min_f64<0x143, 0xc>(r);  // row_bcast:31
    return readlane_f64(r, 63);      // lane 63 holds the full min
}

typedef float fvec48 __attribute__((ext_vector_type(NROW)));

// ---------------- mega kernel: blocks [0,176) = LSA, rest = cost matrix -----
// LSA: JV shortest augmenting path, one problem per wave. The lane's cost
// COLUMN lives in a 48-wide register vector; the wave-uniform row index i0
// (SGPR, via v_readlane) makes the variable extract lower to v_movrels
// (~4 cyc) instead of an LDS read (~120 cyc) -- the LDS read was ~half the
// serial chain. f64 dual arithmetic in reference op order (cost values are
// f32-exact, so the f32->f64 convert is exact).
__global__ __launch_bounds__(256) void mega_kernel(
    const float* __restrict__ logits,
    const float* __restrict__ pboxes,
    const int*   __restrict__ labels,
    const float* __restrict__ tboxes,
    float*       __restrict__ C,
    float*       __restrict__ pi,
    float*       __restrict__ ti)
{
    if (blockIdx.x >= NLSA) {
        long idx = (long)(blockIdx.x - NLSA) * 256 + threadIdx.x;
        if (idx >= (long)BS * NQ * NTOT) return;
        int t = (int)(idx % NTOT);
        int p = (int)(idx / NTOT);
        C[idx] = cost_element(logits, pboxes, labels, tboxes, p, t);
        return;
    }

    // ---- LSA block ----
    const int blk = blockIdx.x;          // 0..175
    const int b = blk / GN, g = blk % GN;
    const int tid = threadIdx.x;

    __shared__ float lcostf[NROW * LPAD];   // [row i][col j], stride 51

    // All 256 threads fill the 48x50 tile, then waves 1-3 exit.
    for (int k = tid; k < NROW * MCOL; k += 256) {
        int i = k % NROW, j = k / NROW;
        lcostf[i * LPAD + j] = cost_element(logits, pboxes, labels, tboxes,
                                            b * NQ + g * GQ + j, b * NT + i);
    }
    __syncthreads();
    if (tid >= 64) return;

    const int lane = tid;
    const bool incol = (lane >= 1 && lane <= MCOL);
    const int cidx = incol ? lane - 1 : 0;
    const double INF = __builtin_inf();

    // Pull this lane's column into registers (constant insert indices).
    fvec48 cv;
#pragma unroll
    for (int i = 0; i < NROW; ++i) cv[i] = lcostf[i * LPAD + cidx];

    int    pcol_l = 0;    // p[lane]   (0 = unassigned)
    double urow_l = 0.0;  // u[p[lane]]
    double v_l    = 0.0;  // v[lane]
    int    way_l  = 0;
    double minv_l = INF;
    bool   used_l = false;

    for (int i = 1; i <= NROW; ++i) {
        if (lane == 0) { pcol_l = i; urow_l = 0.0; }
        minv_l = INF;
        used_l = false;
        int j0 = 0;
        int i0 = i;            // p[j0], wave-uniform
        double u_i0 = 0.0;     // u[i0]

        for (int guard = 0; guard <= MCOL + 1; ++guard) {
            used_l = used_l || (lane == j0);

            float cf = cv[i0 - 1];                    // v_movrels (uniform idx)
            double cd = (double)cf;                   // exact
            bool freel = incol && !used_l;
            double cur = (cd - u_i0) - v_l;           // (cost - u) - v, ref order
            bool upd   = freel && (cur < minv_l);
            minv_l = upd ? cur : minv_l;
            way_l  = upd ? j0  : way_l;

            double val   = freel ? minv_l : INF;
            double delta = wave_min_f64(val);
            unsigned long long mm = __ballot(freel && (minv_l == delta));
            int j1 = (int)__builtin_ctzll(mm);        // lowest lane = np.argmin

            urow_l = used_l ? urow_l + delta : urow_l;
            v_l    = used_l ? v_l - delta    : v_l;
            minv_l = freel  ? minv_l - delta : minv_l;

            int i0n = __builtin_amdgcn_readlane(pcol_l, j1);
            j0 = j1;
            if (i0n == 0) break;
            i0   = i0n;
            u_i0 = readlane_f64(urow_l, j1);
        }

        // augment back-walk: p[j]=p[way[j]], moving urow with pcol
        int j = j0;
        while (j != 0) {
            int wj    = __builtin_amdgcn_readlane(way_l, j);
            int pr    = __builtin_amdgcn_readlane(pcol_l, wj);
            double ur = readlane_f64(urow_l, wj);
            if (lane == j) { pcol_l = pr; urow_l = ur; }
            j = wj;
        }
    }

    // Extraction: ascending query order == reference order after transpose.
    unsigned long long asg = __ballot(incol && pcol_l != 0);
    if (incol && pcol_l != 0) {
        int k = __popcll(asg & ((1ull << lane) - 1));
        float* pib = pi + ((long)b * NPAIR + (long)g * NT);
        float* tib = ti + ((long)b * NPAIR + (long)g * NT);
        pib[k] = (float)(g * GQ + cidx);
        tib[k] = (float)(pcol_l - 1);
    }
}

extern "C" void kernel_launch(void* const* d_in, const int* in_sizes, int n_in,
                              void* d_out, int out_size, void* d_ws, size_t ws_size,
                              hipStream_t stream) {
    const float* logits = (const float*)d_in[0];   // [16,550,91] f32
    const float* pboxes = (const float*)d_in[1];   // [16,550,6] f32
    const int*   labels = (const int*)d_in[2];     // [16,48] i32
    const float* tboxes = (const float*)d_in[3];   // [16,48,6] f32

    float* out = (float*)d_out;
    float* C  = out;                               // 16*550*768
    float* pi = out + (long)BS * NQ * NTOT;
    float* ti = pi + (long)BS * NPAIR;

    long total = (long)BS * NQ * NTOT;
    int cost_blocks = (int)((total + 255) / 256);
    int mega_blocks = NLSA + cost_blocks;

    mega_kernel<<<mega_blocks, 256, 0, stream>>>(
        logits, pboxes, labels, tboxes, C, pi, ti);
}

// Round 6
// 211.790 us; speedup vs baseline: 1.6723x; 1.6723x over previous
//
#include <hip/hip_runtime.h>
#include <math.h>

// Problem constants (setup_inputs: bs=16, nq=550, nc=91, nt=48, group_num=11)
#define BS 16
#define NQ 550
#define NC 91
#define NT 48
#define GN 11
#define GQ 50                 // queries per group
#define NTOT (BS * NT)        // 768
#define NROW 48               // LSA rows (targets) after reference transpose
#define MCOL 50               // LSA cols (queries)
#define NPAIR (GN * NT)       // 528
#define NLSA (BS * GN)        // 176 LSA blocks
#define LPAD 51               // LDS tile row stride (f32)

// ---------------- focal (class) cost: fast f32 (R4-proven) ------------------
__device__ __forceinline__ float focal_cost_f32(float x) {
    float prob = 1.0f / (1.0f + __expf(-x));
    float q = 1.0f - prob;
    float lneg = __logf(q + 1e-8f);
    float lpos = __logf(prob + 1e-8f);
    float neg = 0.75f * (prob * prob) * (-lneg);
    float pos = 0.25f * (q * q) * (-lpos);
    return pos - neg;
}

// ---------------- one C element, f32 __f*_rn box math ------------------------
__device__ __forceinline__ float cost_element(
    const float* __restrict__ logits,
    const float* __restrict__ pboxes, const int* __restrict__ labels,
    const float* __restrict__ tboxes, int p, int t)
{
    const float* pb = pboxes + (long)p * 6;
    float pcx = pb[0], pcy = pb[1], pl = pb[2], pr = pb[3], ptt = pb[4], pbo = pb[5];
    const float* tb = tboxes + (long)t * 6;
    float tcx = tb[0], tcy = tb[1], tl = tb[2], tr = tb[3], ttt = tb[4], tbo = tb[5];

    float c3d = __fadd_rn(fabsf(__fsub_rn(pcx, tcx)), fabsf(__fsub_rn(pcy, tcy)));
    float cbb = __fadd_rn(
                  __fadd_rn(
                    __fadd_rn(fabsf(__fsub_rn(pl, tl)), fabsf(__fsub_rn(pr, tr))),
                    fabsf(__fsub_rn(ptt, ttt))),
                  fabsf(__fsub_rn(pbo, tbo)));

    float px1 = __fsub_rn(pcx, pl), py1 = __fsub_rn(pcy, ptt);
    float px2 = __fadd_rn(pcx, pr), py2 = __fadd_rn(pcy, pbo);
    float tx1 = __fsub_rn(tcx, tl), ty1 = __fsub_rn(tcy, ttt);
    float tx2 = __fadd_rn(tcx, tr), ty2 = __fadd_rn(tcy, tbo);

    float area1 = __fmul_rn(__fsub_rn(px2, px1), __fsub_rn(py2, py1));
    float area2 = __fmul_rn(__fsub_rn(tx2, tx1), __fsub_rn(ty2, ty1));
    float ltx = fmaxf(px1, tx1), lty = fmaxf(py1, ty1);
    float rbx = fminf(px2, tx2), rby = fminf(py2, ty2);
    float wx = fmaxf(__fsub_rn(rbx, ltx), 0.0f);
    float wy = fmaxf(__fsub_rn(rby, lty), 0.0f);
    float inter = __fmul_rn(wx, wy);
    float uni = __fsub_rn(__fadd_rn(area1, area2), inter);
    float iou = __fdiv_rn(inter, uni);
    float ex1 = fminf(px1, tx1), ey1 = fminf(py1, ty1);
    float ex2 = fmaxf(px2, tx2), ey2 = fmaxf(py2, ty2);
    float ew = fmaxf(__fsub_rn(ex2, ex1), 0.0f);
    float eh = fmaxf(__fsub_rn(ey2, ey1), 0.0f);
    float earea = __fmul_rn(ew, eh);
    float giou = __fsub_rn(iou, __fdiv_rn(__fsub_rn(earea, uni), earea));
    float cgiou = -giou;

    float cclass = focal_cost_f32(logits[(long)p * NC + labels[t]]);

    float out = __fmul_rn(5.0f, cbb);
    out = __fadd_rn(out, __fmul_rn(10.0f, c3d));
    out = __fadd_rn(out, __fmul_rn(2.0f, cclass));
    out = __fadd_rn(out, __fmul_rn(2.0f, cgiou));
    return out;
}

// ---------------- cross-lane helpers ----------------------------------------
__device__ __forceinline__ double readlane_f64(double x, int l) {
    long long b = __double_as_longlong(x);
    int lo = __builtin_amdgcn_readlane((int)(b & 0xffffffffLL), l);
    int hi = __builtin_amdgcn_readlane((int)(b >> 32), l);
    return __longlong_as_double(((long long)hi << 32) | (unsigned int)lo);
}

template <int CTRL, int RM>
__device__ __forceinline__ float dpp_min_f32(float x) {
    int b = __float_as_int(x);
    // old = self: lanes with invalid source keep own value (no-op for min)
    int t = __builtin_amdgcn_update_dpp(b, b, CTRL, RM, 0xf, false);
    return fminf(x, __int_as_float(t));
}

// full-wave f32 min, result made uniform via lane 63
__device__ __forceinline__ float wave_min_f32(float val) {
    float r = val;
    r = dpp_min_f32<0x111, 0xf>(r);  // row_shr:1
    r = dpp_min_f32<0x112, 0xf>(r);  // row_shr:2
    r = dpp_min_f32<0x114, 0xf>(r);  // row_shr:4
    r = dpp_min_f32<0x118, 0xf>(r);  // row_shr:8
    r = dpp_min_f32<0x142, 0xa>(r);  // row_bcast:15
    r = dpp_min_f32<0x143, 0xc>(r);  // row_bcast:31
    int bits = __builtin_amdgcn_readlane(__float_as_int(r), 63);
    return __int_as_float(bits);
}

// ---------------- mega kernel: blocks [0,176) = LSA, rest = cost matrix -----
// LSA replicates the reference's e-maxx JV trajectory EXACTLY (u=v=0 init,
// all 48 rows, f64 duals in reference op order, np.argmin lowest-index
// tie-break). R5's column-reduction variant produced a different matching ->
// trajectory-changing optimizations are off the table. The only safe levers
// are per-iteration cycles:
//  * f32 DPP argmin fastpath (monotone f64->f32 => f32-min mask contains the
//    exact f64 argmin; multi-candidate masks resolved by exact f64 readlanes,
//    lowest lane on exact ties). Identical (j1, delta) to pure-f64 reduce.
//  * LDS row prefetch issued right after j1 is known; dual updates hide
//    part of the ~120-cyc ds_read latency.
__global__ __launch_bounds__(256) void mega_kernel(
    const float* __restrict__ logits,
    const float* __restrict__ pboxes,
    const int*   __restrict__ labels,
    const float* __restrict__ tboxes,
    float*       __restrict__ C,
    float*       __restrict__ pi,
    float*       __restrict__ ti)
{
    if (blockIdx.x >= NLSA) {
        long idx = (long)(blockIdx.x - NLSA) * 256 + threadIdx.x;
        if (idx >= (long)BS * NQ * NTOT) return;
        int t = (int)(idx % NTOT);
        int p = (int)(idx / NTOT);
        C[idx] = cost_element(logits, pboxes, labels, tboxes, p, t);
        return;
    }

    // ---- LSA block ----
    const int blk = blockIdx.x;          // 0..175
    const int b = blk / GN, g = blk % GN;
    const int tid = threadIdx.x;

    __shared__ float lcostf[NROW * LPAD];   // [row i][col j], stride 51

    // All 256 threads fill the 48x50 tile, then waves 1-3 exit.
    for (int k = tid; k < NROW * MCOL; k += 256) {
        int i = k % NROW, j = k / NROW;
        lcostf[i * LPAD + j] = cost_element(logits, pboxes, labels, tboxes,
                                            b * NQ + g * GQ + j, b * NT + i);
    }
    __syncthreads();
    if (tid >= 64) return;

    const int lane = tid;
    const bool incol = (lane >= 1 && lane <= MCOL);
    const int cidx = incol ? lane - 1 : 0;
    const double INF = __builtin_inf();
    const float INFF = __builtin_inff();

    int    pcol_l = 0;    // p[lane]   (0 = unassigned)
    double urow_l = 0.0;  // u[p[lane]]
    double v_l    = 0.0;  // v[lane]
    int    way_l  = 0;
    double minv_l = INF;
    bool   used_l = false;

    for (int i = 1; i <= NROW; ++i) {
        if (lane == 0) { pcol_l = i; urow_l = 0.0; }  // p[0]=i, u[i]=0
        minv_l = INF;
        used_l = false;
        int j0 = 0;
        float  cf   = lcostf[(i - 1) * LPAD + cidx];  // prefetch row i
        double u_i0 = 0.0;                            // u[i0]

        for (int guard = 0; guard <= MCOL + 1; ++guard) {
            used_l = used_l || (lane == j0);
            bool freel = incol && !used_l;
            double cur = ((double)cf - u_i0) - v_l;   // (cost - u) - v, ref order
            bool upd   = freel && (cur < minv_l);
            minv_l = upd ? cur : minv_l;
            way_l  = upd ? j0  : way_l;

            // fast f32 argmin; exact f64 resolution on mask collisions
            float mf = freel ? (float)minv_l : INFF;
            float rmin = wave_min_f32(mf);
            unsigned long long mm = __ballot(freel && (mf == rmin));
            int j1 = (int)__builtin_ctzll(mm);
            double delta;
            if (__popcll(mm) > 1) {
                double best = INF; int bj = j1;
                unsigned long long tmask = mm;
                while (tmask) {
                    int l = (int)__builtin_ctzll(tmask);
                    tmask &= tmask - 1;
                    double dv = readlane_f64(minv_l, l);
                    if (dv < best) { best = dv; bj = l; }  // ascending: lowest lane wins exact ties
                }
                j1 = bj; delta = best;
            } else {
                delta = readlane_f64(minv_l, j1);
            }

            // issue next row's LDS read ASAP; dual updates hide its latency
            int i0n = __builtin_amdgcn_readlane(pcol_l, j1);
            int li = (i0n > 0 ? i0n : 1) - 1;
            cf = lcostf[li * LPAD + cidx];

            urow_l = used_l ? urow_l + delta : urow_l;
            v_l    = used_l ? v_l - delta    : v_l;
            minv_l = freel  ? minv_l - delta : minv_l;

            j0 = j1;
            if (i0n == 0) break;
            u_i0 = readlane_f64(urow_l, j1);          // after updates, as ref
        }

        // augment back-walk: p[j]=p[way[j]], moving urow with pcol
        int j = j0;
        while (j != 0) {
            int wj    = __builtin_amdgcn_readlane(way_l, j);
            int pr    = __builtin_amdgcn_readlane(pcol_l, wj);
            double ur = readlane_f64(urow_l, wj);
            if (lane == j) { pcol_l = pr; urow_l = ur; }
            j = wj;
        }
    }

    // Extraction: ascending query (column) order == reference order.
    unsigned long long asg = __ballot(incol && pcol_l != 0);
    if (incol && pcol_l != 0) {
        int k = __popcll(asg & ((1ull << lane) - 1));
        float* pib = pi + ((long)b * NPAIR + (long)g * NT);
        float* tib = ti + ((long)b * NPAIR + (long)g * NT);
        pib[k] = (float)(g * GQ + cidx);
        tib[k] = (float)(pcol_l - 1);
    }
}

extern "C" void kernel_launch(void* const* d_in, const int* in_sizes, int n_in,
                              void* d_out, int out_size, void* d_ws, size_t ws_size,
                              hipStream_t stream) {
    const float* logits = (const float*)d_in[0];   // [16,550,91] f32
    const float* pboxes = (const float*)d_in[1];   // [16,550,6] f32
    const int*   labels = (const int*)d_in[2];     // [16,48] i32
    const float* tboxes = (const float*)d_in[3];   // [16,48,6] f32

    float* out = (float*)d_out;
    float* C  = out;                               // 16*550*768
    float* pi = out + (long)BS * NQ * NTOT;
    float* ti = pi + (long)BS * NPAIR;

    long total = (long)BS * NQ * NTOT;
    int cost_blocks = (int)((total + 255) / 256);
    int mega_blocks = NLSA + cost_blocks;

    mega_kernel<<<mega_blocks, 256, 0, stream>>>(
        logits, pboxes, labels, tboxes, C, pi, ti);
}

// Round 7
// 178.070 us; speedup vs baseline: 1.9890x; 1.1894x over previous
//
#include <hip/hip_runtime.h>
#include <math.h>

// Problem constants (setup_inputs: bs=16, nq=550, nc=91, nt=48, group_num=11)
#define BS 16
#define NQ 550
#define NC 91
#define NT 48
#define GN 11
#define GQ 50                 // queries per group
#define NTOT (BS * NT)        // 768
#define NROW 48               // LSA rows (targets) after reference transpose
#define MCOL 50               // LSA cols (queries)
#define NPAIR (GN * NT)       // 528
#define NLSA (BS * GN)        // 176 LSA blocks

// ---------------- focal (class) cost: fast f32 (R4/R6-proven) ---------------
__device__ __forceinline__ float focal_cost_f32(float x) {
    float prob = 1.0f / (1.0f + __expf(-x));
    float q = 1.0f - prob;
    float lneg = __logf(q + 1e-8f);
    float lpos = __logf(prob + 1e-8f);
    float neg = 0.75f * (prob * prob) * (-lneg);
    float pos = 0.25f * (q * q) * (-lpos);
    return pos - neg;
}

// ---------------- one C element, f32 __f*_rn box math ------------------------
__device__ __forceinline__ float cost_element(
    const float* __restrict__ logits,
    const float* __restrict__ pboxes, const int* __restrict__ labels,
    const float* __restrict__ tboxes, int p, int t)
{
    const float* pb = pboxes + (long)p * 6;
    float pcx = pb[0], pcy = pb[1], pl = pb[2], pr = pb[3], ptt = pb[4], pbo = pb[5];
    const float* tb = tboxes + (long)t * 6;
    float tcx = tb[0], tcy = tb[1], tl = tb[2], tr = tb[3], ttt = tb[4], tbo = tb[5];

    float c3d = __fadd_rn(fabsf(__fsub_rn(pcx, tcx)), fabsf(__fsub_rn(pcy, tcy)));
    float cbb = __fadd_rn(
                  __fadd_rn(
                    __fadd_rn(fabsf(__fsub_rn(pl, tl)), fabsf(__fsub_rn(pr, tr))),
                    fabsf(__fsub_rn(ptt, ttt))),
                  fabsf(__fsub_rn(pbo, tbo)));

    float px1 = __fsub_rn(pcx, pl), py1 = __fsub_rn(pcy, ptt);
    float px2 = __fadd_rn(pcx, pr), py2 = __fadd_rn(pcy, pbo);
    float tx1 = __fsub_rn(tcx, tl), ty1 = __fsub_rn(tcy, ttt);
    float tx2 = __fadd_rn(tcx, tr), ty2 = __fadd_rn(tcy, tbo);

    float area1 = __fmul_rn(__fsub_rn(px2, px1), __fsub_rn(py2, py1));
    float area2 = __fmul_rn(__fsub_rn(tx2, tx1), __fsub_rn(ty2, ty1));
    float ltx = fmaxf(px1, tx1), lty = fmaxf(py1, ty1);
    float rbx = fminf(px2, tx2), rby = fminf(py2, ty2);
    float wx = fmaxf(__fsub_rn(rbx, ltx), 0.0f);
    float wy = fmaxf(__fsub_rn(rby, lty), 0.0f);
    float inter = __fmul_rn(wx, wy);
    float uni = __fsub_rn(__fadd_rn(area1, area2), inter);
    float iou = __fdiv_rn(inter, uni);
    float ex1 = fminf(px1, tx1), ey1 = fminf(py1, ty1);
    float ex2 = fmaxf(px2, tx2), ey2 = fmaxf(py2, ty2);
    float ew = fmaxf(__fsub_rn(ex2, ex1), 0.0f);
    float eh = fmaxf(__fsub_rn(ey2, ey1), 0.0f);
    float earea = __fmul_rn(ew, eh);
    float giou = __fsub_rn(iou, __fdiv_rn(__fsub_rn(earea, uni), earea));
    float cgiou = -giou;

    float cclass = focal_cost_f32(logits[(long)p * NC + labels[t]]);

    float out = __fmul_rn(5.0f, cbb);
    out = __fadd_rn(out, __fmul_rn(10.0f, c3d));
    out = __fadd_rn(out, __fmul_rn(2.0f, cclass));
    out = __fadd_rn(out, __fmul_rn(2.0f, cgiou));
    return out;
}

// ---------------- cross-lane f64 helpers (R3-proven) ------------------------
__device__ __forceinline__ double readlane_f64(double x, int l) {
    long long b = __double_as_longlong(x);
    int lo = __builtin_amdgcn_readlane((int)(b & 0xffffffffLL), l);
    int hi = __builtin_amdgcn_readlane((int)(b >> 32), l);
    return __longlong_as_double(((long long)hi << 32) | (unsigned int)lo);
}

template <int CTRL, int RM>
__device__ __forceinline__ double dpp_min_f64(double x) {
    long long b = __double_as_longlong(x);
    int lo = (int)(b & 0xffffffffLL);
    int hi = (int)(b >> 32);
    int tlo = __builtin_amdgcn_update_dpp(lo, lo, CTRL, RM, 0xf, false);
    int thi = __builtin_amdgcn_update_dpp(hi, hi, CTRL, RM, 0xf, false);
    double t = __longlong_as_double(((long long)thi << 32) | (unsigned int)tlo);
    return fmin(x, t);   // v_min_f64; NaNs impossible here
}

__device__ __forceinline__ double wave_min_f64(double val) {
    double r = val;
    r = dpp_min_f64<0x111, 0xf>(r);  // row_shr:1
    r = dpp_min_f64<0x112, 0xf>(r);  // row_shr:2
    r = dpp_min_f64<0x114, 0xf>(r);  // row_shr:4
    r = dpp_min_f64<0x118, 0xf>(r);  // row_shr:8
    r = dpp_min_f64<0x142, 0xa>(r);  // row_bcast:15
    r = dpp_min_f64<0x143, 0xc>(r);  // row_bcast:31
    return readlane_f64(r, 63);      // lane 63 holds the full min
}

// ---------------- mega kernel: blocks [0,176) = LSA, rest = cost matrix -----
// LSA = R3's verified 123-us inner loop VERBATIM (branch-free f64 DPP reduce,
// delta straight from the reduce, f64 LDS tile). R6's f32-fastpath+prefetch
// variant regressed to 152 us — reverted. Shell = R6's single fused launch
// (no focal-table kernel). One identity tweak: u_i0 readlane issued before
// the dual updates (column j1 is free this iteration, so urow[j1] is not
// modified by them — bit-identical value, shorter tail).
__global__ __launch_bounds__(256) void mega_kernel(
    const float* __restrict__ logits,
    const float* __restrict__ pboxes,
    const int*   __restrict__ labels,
    const float* __restrict__ tboxes,
    float*       __restrict__ C,
    float*       __restrict__ pi,
    float*       __restrict__ ti)
{
    if (blockIdx.x >= NLSA) {
        long idx = (long)(blockIdx.x - NLSA) * 256 + threadIdx.x;
        if (idx >= (long)BS * NQ * NTOT) return;
        int t = (int)(idx % NTOT);
        int p = (int)(idx / NTOT);
        C[idx] = cost_element(logits, pboxes, labels, tboxes, p, t);
        return;
    }

    // ---- LSA block ----
    const int blk = blockIdx.x;          // 0..175
    const int b = blk / GN, g = blk % GN;
    const int tid = threadIdx.x;

    __shared__ double lcost[NROW * MCOL];   // [row i][col j]

    // All 256 threads fill the 48x50 tile, then waves 1-3 exit.
    for (int k = tid; k < NROW * MCOL; k += 256) {
        int i = k % NROW, j = k / NROW;
        float cf = cost_element(logits, pboxes, labels, tboxes,
                                b * NQ + g * GQ + j, b * NT + i);
        lcost[i * MCOL + j] = (double)cf;
    }
    __syncthreads();
    if (tid >= 64) return;

    const int lane = tid;
    const bool incol = (lane >= 1 && lane <= MCOL);
    const int cidx = incol ? lane - 1 : 0;
    const double INF = __builtin_inf();

    int    pcol_l = 0;    // p[lane]   (0 = unassigned)
    double urow_l = 0.0;  // u[p[lane]]
    double v_l    = 0.0;  // v[lane]
    int    way_l  = 0;
    double minv_l = INF;
    bool   used_l = false;

    for (int i = 1; i <= NROW; ++i) {
        if (lane == 0) { pcol_l = i; urow_l = 0.0; }  // p[0]=i, u[i]=0
        minv_l = INF;
        used_l = false;
        int j0 = 0;
        int i0 = i;            // p[j0], wave-uniform
        double u_i0 = 0.0;     // u[i0]

        for (int guard = 0; guard <= MCOL + 1; ++guard) {
            used_l = used_l || (lane == j0);

            double cd  = lcost[(i0 - 1) * MCOL + cidx];
            bool freel = incol && !used_l;
            double cur = (cd - u_i0) - v_l;           // (cost - u) - v, ref order
            bool upd   = freel && (cur < minv_l);
            minv_l = upd ? cur : minv_l;
            way_l  = upd ? j0  : way_l;

            double val   = freel ? minv_l : INF;
            double delta = wave_min_f64(val);
            unsigned long long mm = __ballot(freel && (minv_l == delta));
            int j1 = (int)__builtin_ctzll(mm);        // lowest lane = np.argmin

            // both readlanes issued before the dual updates; urow[j1] is not
            // touched by this iteration's update (lane j1 is free), so the
            // value is identical to reading it afterwards.
            int    i0n  = __builtin_amdgcn_readlane(pcol_l, j1);
            double u_nx = readlane_f64(urow_l, j1);

            urow_l = used_l ? urow_l + delta : urow_l;
            v_l    = used_l ? v_l - delta    : v_l;
            minv_l = freel  ? minv_l - delta : minv_l;

            j0 = j1;
            if (i0n == 0) break;
            i0   = i0n;
            u_i0 = u_nx;
        }

        // augment back-walk: p[j]=p[way[j]], moving urow with pcol
        int j = j0;
        while (j != 0) {
            int wj    = __builtin_amdgcn_readlane(way_l, j);
            int pr    = __builtin_amdgcn_readlane(pcol_l, wj);
            double ur = readlane_f64(urow_l, wj);
            if (lane == j) { pcol_l = pr; urow_l = ur; }
            j = wj;
        }
    }

    // Extraction: ascending query (column) order == reference order.
    unsigned long long asg = __ballot(incol && pcol_l != 0);
    if (incol && pcol_l != 0) {
        int k = __popcll(asg & ((1ull << lane) - 1));
        float* pib = pi + ((long)b * NPAIR + (long)g * NT);
        float* tib = ti + ((long)b * NPAIR + (long)g * NT);
        pib[k] = (float)(g * GQ + cidx);
        tib[k] = (float)(pcol_l - 1);
    }
}

extern "C" void kernel_launch(void* const* d_in, const int* in_sizes, int n_in,
                              void* d_out, int out_size, void* d_ws, size_t ws_size,
                              hipStream_t stream) {
    const float* logits = (const float*)d_in[0];   // [16,550,91] f32
    const float* pboxes = (const float*)d_in[1];   // [16,550,6] f32
    const int*   labels = (const int*)d_in[2];     // [16,48] i32
    const float* tboxes = (const float*)d_in[3];   // [16,48,6] f32

    float* out = (float*)d_out;
    float* C  = out;                               // 16*550*768
    float* pi = out + (long)BS * NQ * NTOT;
    float* ti = pi + (long)BS * NPAIR;

    long total = (long)BS * NQ * NTOT;
    int cost_blocks = (int)((total + 255) / 256);
    int mega_blocks = NLSA + cost_blocks;

    mega_kernel<<<mega_blocks, 256, 0, stream>>>(
        logits, pboxes, labels, tboxes, C, pi, ti);
}